// Round 2
// baseline (1304.133 us; speedup 1.0000x reference)
//
#include <hip/hip_runtime.h>
#include <hip/hip_bf16.h>

#define B_ 2
#define S_ 2048
#define D_ 1024
#define H_ 16
#define DK_ 64
#define BS_ (B_ * S_)   // 4096

typedef unsigned int u32;
typedef unsigned short u16;

__device__ __forceinline__ float bf2f(u16 v) {
    union { u32 u; float f; } c; c.u = ((u32)v) << 16; return c.f;
}
// round-to-nearest-even f32 -> bf16
__device__ __forceinline__ u16 f2bf(float f) {
    union { float f; u32 u; } c; c.f = f;
    u32 u = c.u;
    u32 r = (u + 0x7fffu + ((u >> 16) & 1u)) >> 16;
    return (u16)r;
}
__device__ __forceinline__ u32 pack2(float a, float b) {
    return (u32)f2bf(a) | ((u32)f2bf(b) << 16);
}

// C[r][c] = sum_d X[r][d] * W(d,c) + bias[c]   (all float32)
// headMode=1: W is [H][D][DK], c=(h*64+k) -> idx = (c>>6)*D_*DK_ + d*DK_ + (c&63)
// headMode=0: W is [D][D] row-major -> idx = d*D_ + c
__global__ __launch_bounds__(256) void proj_kernel(
    const float* __restrict__ X, const float* __restrict__ W,
    const float* __restrict__ bias, float* __restrict__ Y, int headMode)
{
    __shared__ float As[16][68];  // As[kk][m]
    __shared__ float Bs[16][68];  // Bs[kk][n]
    const int tid = threadIdx.x;
    const int tx = tid & 15, ty = tid >> 4;
    const int tx4 = tx * 4, ty4 = ty * 4;
    const int row0 = blockIdx.x * 64;
    const int col0 = blockIdx.y * 64;

    const int lm = tid >> 2;         // X row in tile   0..63
    const int lk = (tid & 3) * 4;    // X col in k-tile {0,4,8,12}
    const int wk = tid >> 4;         // W row in k-tile 0..15
    const int wn = (tid & 15) * 4;   // W col in tile   {0,4,...,60}

    float acc[4][4] = {};

    for (int k0 = 0; k0 < D_; k0 += 16) {
        __syncthreads();
        {   // X tile 64x16 (transposed into As[kk][m])
            const float* p = X + (row0 + lm) * D_ + k0 + lk;
            float4 a = *(const float4*)p;
            As[lk + 0][lm] = a.x;
            As[lk + 1][lm] = a.y;
            As[lk + 2][lm] = a.z;
            As[lk + 3][lm] = a.w;
        }
        {   // W tile 16x64
            const int c = col0 + wn;
            const int d = k0 + wk;
            const float* p = headMode
                ? (W + (c >> 6) * (D_ * DK_) + d * DK_ + (c & 63))
                : (W + d * D_ + c);
            float4 b = *(const float4*)p;
            Bs[wk][wn + 0] = b.x;
            Bs[wk][wn + 1] = b.y;
            Bs[wk][wn + 2] = b.z;
            Bs[wk][wn + 3] = b.w;
        }
        __syncthreads();
        #pragma unroll
        for (int kk = 0; kk < 16; ++kk) {
            float4 av = *(const float4*)&As[kk][ty4];
            float4 bv = *(const float4*)&Bs[kk][tx4];
            float a4[4] = {av.x, av.y, av.z, av.w};
            float b4[4] = {bv.x, bv.y, bv.z, bv.w};
            #pragma unroll
            for (int i = 0; i < 4; ++i)
                #pragma unroll
                for (int j = 0; j < 4; ++j)
                    acc[i][j] += a4[i] * b4[j];
        }
    }

    const int c = col0 + tx4;
    float4 bb = *(const float4*)(bias + c);
    #pragma unroll
    for (int i = 0; i < 4; ++i) {
        const int r = row0 + ty4 + i;
        float4 o;
        o.x = acc[i][0] + bb.x;
        o.y = acc[i][1] + bb.y;
        o.z = acc[i][2] + bb.z;
        o.w = acc[i][3] + bb.w;
        *(float4*)(Y + r * D_ + c) = o;
    }
}

// Fused batch-axis-softmax attention. (softmax over B=2 -> per-pair sigmoid)
// Q,K,V: [B][S][H*DK] f32 (projected). Cc: [B][S][H*DK] f32.
// O[b][s][k] = sum_t sigmoid((S_b - S_{1-b})[s][t]) * V[b][t][k],
// S_b[s][t] = (1/8) * sum_k Q[b][s][k]*K[b][t][k].
// LDS tiles staged as bf16 (fits 64KB; 2% tolerance >> bf16 rounding).
__global__ __launch_bounds__(256) void attn_kernel(
    const float* __restrict__ Qg, const float* __restrict__ Kg,
    const float* __restrict__ Vg, float* __restrict__ Cc)
{
    __shared__ u16 Qs[2][64][68];
    __shared__ u16 Ks[2][64][68];
    __shared__ u16 Vs[2][64][68];
    __shared__ u16 Ps[64][68];

    const int tid = threadIdx.x;
    const int tx = tid & 15, ty = tid >> 4;
    const int tx4 = tx * 4, ty4 = ty * 4;
    const int s0 = blockIdx.x * 64;
    const int h  = blockIdx.y;

    const int ls = tid >> 2;        // 0..63 row in tile
    const int lc = (tid & 3) * 16;  // {0,16,32,48} col in tile

    // Q tiles for both batches: f32 global -> bf16 LDS
    #pragma unroll
    for (int b = 0; b < 2; ++b) {
        const float* p = Qg + ((size_t)(b * S_ + s0 + ls) * D_ + h * DK_ + lc);
        float4 a0 = *(const float4*)(p + 0);
        float4 a1 = *(const float4*)(p + 4);
        float4 a2 = *(const float4*)(p + 8);
        float4 a3 = *(const float4*)(p + 12);
        u32* dst = (u32*)&Qs[b][ls][lc];
        dst[0] = pack2(a0.x, a0.y); dst[1] = pack2(a0.z, a0.w);
        dst[2] = pack2(a1.x, a1.y); dst[3] = pack2(a1.z, a1.w);
        dst[4] = pack2(a2.x, a2.y); dst[5] = pack2(a2.z, a2.w);
        dst[6] = pack2(a3.x, a3.y); dst[7] = pack2(a3.z, a3.w);
    }

    float O0[4][4] = {}, O1[4][4] = {};

    for (int t0 = 0; t0 < S_; t0 += 64) {
        __syncthreads();
        #pragma unroll
        for (int b = 0; b < 2; ++b) {
            const float* pk = Kg + ((size_t)(b * S_ + t0 + ls) * D_ + h * DK_ + lc);
            float4 a0 = *(const float4*)(pk + 0);
            float4 a1 = *(const float4*)(pk + 4);
            float4 a2 = *(const float4*)(pk + 8);
            float4 a3 = *(const float4*)(pk + 12);
            u32* dk_ = (u32*)&Ks[b][ls][lc];
            dk_[0] = pack2(a0.x, a0.y); dk_[1] = pack2(a0.z, a0.w);
            dk_[2] = pack2(a1.x, a1.y); dk_[3] = pack2(a1.z, a1.w);
            dk_[4] = pack2(a2.x, a2.y); dk_[5] = pack2(a2.z, a2.w);
            dk_[6] = pack2(a3.x, a3.y); dk_[7] = pack2(a3.z, a3.w);
            const float* pv = Vg + ((size_t)(b * S_ + t0 + ls) * D_ + h * DK_ + lc);
            float4 b0 = *(const float4*)(pv + 0);
            float4 b1 = *(const float4*)(pv + 4);
            float4 b2 = *(const float4*)(pv + 8);
            float4 b3 = *(const float4*)(pv + 12);
            u32* dv = (u32*)&Vs[b][ls][lc];
            dv[0] = pack2(b0.x, b0.y); dv[1] = pack2(b0.z, b0.w);
            dv[2] = pack2(b1.x, b1.y); dv[3] = pack2(b1.z, b1.w);
            dv[4] = pack2(b2.x, b2.y); dv[5] = pack2(b2.z, b2.w);
            dv[6] = pack2(b3.x, b3.y); dv[7] = pack2(b3.z, b3.w);
        }
        __syncthreads();

        // ---- scores for this t-tile ----
        float acc0[4][4] = {}, acc1[4][4] = {};
        #pragma unroll 8
        for (int kk = 0; kk < 64; kk += 2) {
            float q0l[4], q0h[4], q1l[4], q1h[4];
            float k0l[4], k0h[4], k1l[4], k1h[4];
            #pragma unroll
            for (int i = 0; i < 4; ++i) {
                u32 u = *(const u32*)&Qs[0][ty4 + i][kk];
                q0l[i] = bf2f((u16)u); q0h[i] = bf2f((u16)(u >> 16));
                u = *(const u32*)&Qs[1][ty4 + i][kk];
                q1l[i] = bf2f((u16)u); q1h[i] = bf2f((u16)(u >> 16));
            }
            #pragma unroll
            for (int j = 0; j < 4; ++j) {
                u32 u = *(const u32*)&Ks[0][tx4 + j][kk];
                k0l[j] = bf2f((u16)u); k0h[j] = bf2f((u16)(u >> 16));
                u = *(const u32*)&Ks[1][tx4 + j][kk];
                k1l[j] = bf2f((u16)u); k1h[j] = bf2f((u16)(u >> 16));
            }
            #pragma unroll
            for (int i = 0; i < 4; ++i)
                #pragma unroll
                for (int j = 0; j < 4; ++j) {
                    acc0[i][j] += q0l[i] * k0l[j] + q0h[i] * k0h[j];
                    acc1[i][j] += q1l[i] * k1l[j] + q1h[i] * k1h[j];
                }
        }
        #pragma unroll
        for (int i = 0; i < 4; ++i) {
            float p[4];
            #pragma unroll
            for (int j = 0; j < 4; ++j) {
                float dlt = (acc0[i][j] - acc1[i][j]) * 0.125f;
                p[j] = 1.0f / (1.0f + __expf(-dlt));
            }
            *(u32*)&Ps[ty4 + i][tx4]     = pack2(p[0], p[1]);
            *(u32*)&Ps[ty4 + i][tx4 + 2] = pack2(p[2], p[3]);
        }
        __syncthreads();

        // ---- O += P * V ----
        #pragma unroll 8
        for (int jj = 0; jj < 64; jj += 2) {
            float pa[4], pb[4];
            #pragma unroll
            for (int i = 0; i < 4; ++i) {
                u32 u = *(const u32*)&Ps[ty4 + i][jj];
                pa[i] = bf2f((u16)u); pb[i] = bf2f((u16)(u >> 16));
            }
            float v0a[4], v0b[4], v1a[4], v1b[4];
            {
                const u32* r = (const u32*)&Vs[0][jj][tx4];
                v0a[0] = bf2f((u16)r[0]); v0a[1] = bf2f((u16)(r[0] >> 16));
                v0a[2] = bf2f((u16)r[1]); v0a[3] = bf2f((u16)(r[1] >> 16));
                r = (const u32*)&Vs[0][jj + 1][tx4];
                v0b[0] = bf2f((u16)r[0]); v0b[1] = bf2f((u16)(r[0] >> 16));
                v0b[2] = bf2f((u16)r[1]); v0b[3] = bf2f((u16)(r[1] >> 16));
                r = (const u32*)&Vs[1][jj][tx4];
                v1a[0] = bf2f((u16)r[0]); v1a[1] = bf2f((u16)(r[0] >> 16));
                v1a[2] = bf2f((u16)r[1]); v1a[3] = bf2f((u16)(r[1] >> 16));
                r = (const u32*)&Vs[1][jj + 1][tx4];
                v1b[0] = bf2f((u16)r[0]); v1b[1] = bf2f((u16)(r[0] >> 16));
                v1b[2] = bf2f((u16)r[1]); v1b[3] = bf2f((u16)(r[1] >> 16));
            }
            #pragma unroll
            for (int i = 0; i < 4; ++i) {
                const float qa = pa[i], qb = pb[i];
                const float ca = 1.0f - pa[i], cb = 1.0f - pb[i];
                #pragma unroll
                for (int j = 0; j < 4; ++j) {
                    O0[i][j] += qa * v0a[j] + qb * v0b[j];
                    O1[i][j] += ca * v1a[j] + cb * v1b[j];
                }
            }
        }
    }

    // epilogue: concat layout [B][S][H*DK], f32
    #pragma unroll
    for (int i = 0; i < 4; ++i) {
        {
            float* dst = Cc + ((size_t)(0 * S_ + s0 + ty4 + i) * D_ + h * DK_ + tx4);
            float4 o = {O0[i][0], O0[i][1], O0[i][2], O0[i][3]};
            *(float4*)dst = o;
        }
        {
            float* dst = Cc + ((size_t)(1 * S_ + s0 + ty4 + i) * D_ + h * DK_ + tx4);
            float4 o = {O1[i][0], O1[i][1], O1[i][2], O1[i][3]};
            *(float4*)dst = o;
        }
    }
}

extern "C" void kernel_launch(void* const* d_in, const int* in_sizes, int n_in,
                              void* d_out, int out_size, void* d_ws, size_t ws_size,
                              hipStream_t stream) {
    const float* q  = (const float*)d_in[0];
    const float* k  = (const float*)d_in[1];
    const float* v  = (const float*)d_in[2];
    const float* Wq = (const float*)d_in[3];
    const float* bq = (const float*)d_in[4];
    const float* Wk = (const float*)d_in[5];
    const float* bk = (const float*)d_in[6];
    const float* Wv = (const float*)d_in[7];
    const float* bv = (const float*)d_in[8];
    const float* Wo = (const float*)d_in[9];
    const float* bo = (const float*)d_in[10];

    float* ws = (float*)d_ws;
    float* Qp = ws;
    float* Kp = ws + (size_t)BS_ * D_;
    float* Vp = ws + (size_t)2 * BS_ * D_;
    float* Cc = ws + (size_t)3 * BS_ * D_;
    float* out = (float*)d_out;

    dim3 block(256);
    dim3 gridP(BS_ / 64, D_ / 64);   // 64 x 16
    dim3 gridA(S_ / 64, H_);         // 32 x 16

    proj_kernel<<<gridP, block, 0, stream>>>(q, Wq, bq, Qp, 1);
    proj_kernel<<<gridP, block, 0, stream>>>(k, Wk, bk, Kp, 1);
    proj_kernel<<<gridP, block, 0, stream>>>(v, Wv, bv, Vp, 1);
    attn_kernel<<<gridA, block, 0, stream>>>(Qp, Kp, Vp, Cc);
    proj_kernel<<<gridP, block, 0, stream>>>(Cc, Wo, bo, out, 0);
}

// Round 3
// 355.326 us; speedup vs baseline: 3.6702x; 3.6702x over previous
//
#include <hip/hip_runtime.h>
#include <hip/hip_bf16.h>

#define B_ 2
#define S_ 2048
#define D_ 1024
#define H_ 16
#define DK_ 64
#define BS_ (B_ * S_)   // 4096

typedef unsigned int u32;
typedef unsigned short u16;
typedef __attribute__((ext_vector_type(8))) short bf16x8;
typedef __attribute__((ext_vector_type(4))) float f32x4;

__device__ __forceinline__ float bf2f(u16 v) {
    union { u32 u; float f; } c; c.u = ((u32)v) << 16; return c.f;
}
__device__ __forceinline__ u16 f2bf(float f) {
    union { float f; u32 u; } c; c.f = f;
    u32 u = c.u;
    u32 r = (u + 0x7fffu + ((u >> 16) & 1u)) >> 16;
    return (u16)r;
}
__device__ __forceinline__ u32 pack2(float a, float b) {
    return (u32)f2bf(a) | ((u32)f2bf(b) << 16);
}

// ---------------- f32 -> bf16 elementwise convert ----------------
__global__ __launch_bounds__(256) void convert_bf16(
    const float* __restrict__ X, u16* __restrict__ Y, int n)
{
    int i = (blockIdx.x * 256 + threadIdx.x) * 8;
    if (i < n) {
        float4 a = *(const float4*)(X + i);
        float4 b = *(const float4*)(X + i + 4);
        uint4 o;
        o.x = pack2(a.x, a.y); o.y = pack2(a.z, a.w);
        o.z = pack2(b.x, b.y); o.w = pack2(b.z, b.w);
        *(uint4*)(Y + i) = o;
    }
}

// ---------------- weight transpose+convert: WT[n][k] bf16 ----------------
// headMode=1: W is [H][1024][64] f32, column n=(h*64+ck):  W[n>>6][k][n&63]
// headMode=0: W is [1024][1024] f32 row-major:             W[k][n]
__global__ __launch_bounds__(256) void transpose_w(
    const float* __restrict__ W, u16* __restrict__ WT, int headMode)
{
    __shared__ __attribute__((aligned(16))) u16 T[64][72];
    const int tid = threadIdx.x;
    const int k0 = blockIdx.x * 64;
    const int n0 = blockIdx.y * 64;
    const int kr = tid >> 4;          // 0..15
    const int n4 = (tid & 15) * 4;
    #pragma unroll
    for (int pass = 0; pass < 4; ++pass) {
        int kk = k0 + pass * 16 + kr;
        const float* p = headMode
            ? (W + (size_t)((n0 + n4) >> 6) * (1024 * 64) + kk * 64 + ((n0 + n4) & 63))
            : (W + (size_t)kk * 1024 + n0 + n4);
        float4 a = *(const float4*)p;
        int krel = pass * 16 + kr;
        T[n4 + 0][krel] = f2bf(a.x);
        T[n4 + 1][krel] = f2bf(a.y);
        T[n4 + 2][krel] = f2bf(a.z);
        T[n4 + 3][krel] = f2bf(a.w);
    }
    __syncthreads();
    const int nr = tid >> 2;
    const int kq = (tid & 3) * 16;
    uint4 o0 = *(const uint4*)&T[nr][kq];
    uint4 o1 = *(const uint4*)&T[nr][kq + 8];
    u16* q = WT + (size_t)(n0 + nr) * 1024 + k0 + kq;
    *(uint4*)q = o0;
    *(uint4*)(q + 8) = o1;
}

// ---------------- V transpose: VT[b][h][dk][t] = Vb[b][t][h*64+dk] ----------------
__global__ __launch_bounds__(256) void transpose_v(
    const u16* __restrict__ Vb, u16* __restrict__ VT)
{
    __shared__ __attribute__((aligned(16))) u16 T[64][72];
    const int tid = threadIdx.x;
    const int t0 = blockIdx.x * 64;
    const int bh = blockIdx.y;      // b*16+h
    const int b = bh >> 4, h = bh & 15;
    const int tr = tid >> 4;        // 0..15
    const int d4 = (tid & 15) * 4;
    #pragma unroll
    for (int pass = 0; pass < 4; ++pass) {
        int tt = t0 + pass * 16 + tr;
        const u16* p = Vb + (size_t)(b * S_ + tt) * 1024 + h * 64 + d4;
        u32 a = *(const u32*)p;
        u32 c = *(const u32*)(p + 2);
        int trel = pass * 16 + tr;
        T[d4 + 0][trel] = (u16)a;
        T[d4 + 1][trel] = (u16)(a >> 16);
        T[d4 + 2][trel] = (u16)c;
        T[d4 + 3][trel] = (u16)(c >> 16);
    }
    __syncthreads();
    const int dr = tid >> 2;
    const int tq = (tid & 3) * 16;
    uint4 o0 = *(const uint4*)&T[dr][tq];
    uint4 o1 = *(const uint4*)&T[dr][tq + 8];
    u16* q = VT + ((size_t)bh * 64 + dr) * 2048 + t0 + tq;
    *(uint4*)q = o0;
    *(uint4*)(q + 8) = o1;
}

// ---------------- bf16 MFMA GEMM, B^T input ----------------
// Y[M][1024] = X[M][1024]bf16 . WT^T + bias;   WT is [1024 n][1024 k] bf16.
// 128x128 tile, 4 waves each 64x64, BK=32.
__global__ __launch_bounds__(256) void gemm_bt(
    const u16* __restrict__ X, const u16* __restrict__ WT,
    const float* __restrict__ bias, void* __restrict__ Yv, int out_f32)
{
    __shared__ __attribute__((aligned(16))) u16 As[128][40];
    __shared__ __attribute__((aligned(16))) u16 Bs[128][40];
    const int tid = threadIdx.x;
    const int lane = tid & 63;
    const int wave = tid >> 6;
    const int quad = lane >> 4;
    const int l16 = lane & 15;
    const int m0 = blockIdx.x * 128;
    const int n0 = blockIdx.y * 128;
    const int wm = (wave & 1) * 64, wn = (wave >> 1) * 64;

    const int srow = tid >> 1;          // 0..127
    const int scol = (tid & 1) * 16;    // 0 or 16

    f32x4 acc[4][4] = {};               // [mt][nt]

    for (int k0 = 0; k0 < 1024; k0 += 32) {
        __syncthreads();
        {
            const u16* p = X + (size_t)(m0 + srow) * 1024 + k0 + scol;
            *(uint4*)&As[srow][scol]     = *(const uint4*)p;
            *(uint4*)&As[srow][scol + 8] = *(const uint4*)(p + 8);
            const u16* q = WT + (size_t)(n0 + srow) * 1024 + k0 + scol;
            *(uint4*)&Bs[srow][scol]     = *(const uint4*)q;
            *(uint4*)&Bs[srow][scol + 8] = *(const uint4*)(q + 8);
        }
        __syncthreads();
        bf16x8 af[4], bfr[4];
        #pragma unroll
        for (int mt = 0; mt < 4; ++mt)
            af[mt] = *(const bf16x8*)&As[wm + mt * 16 + l16][quad * 8];
        #pragma unroll
        for (int nt = 0; nt < 4; ++nt)
            bfr[nt] = *(const bf16x8*)&Bs[wn + nt * 16 + l16][quad * 8];
        #pragma unroll
        for (int mt = 0; mt < 4; ++mt)
            #pragma unroll
            for (int nt = 0; nt < 4; ++nt)
                acc[mt][nt] = __builtin_amdgcn_mfma_f32_16x16x32_bf16(
                    af[mt], bfr[nt], acc[mt][nt], 0, 0, 0);
    }

    #pragma unroll
    for (int nt = 0; nt < 4; ++nt) {
        const int col = n0 + wn + nt * 16 + l16;
        const float bv = bias[col];
        #pragma unroll
        for (int mt = 0; mt < 4; ++mt) {
            #pragma unroll
            for (int r = 0; r < 4; ++r) {
                const int row = m0 + wm + mt * 16 + quad * 4 + r;
                const float v = acc[mt][nt][r] + bv;
                if (out_f32) ((float*)Yv)[(size_t)row * 1024 + col] = v;
                else         ((u16*)Yv)[(size_t)row * 1024 + col] = f2bf(v);
            }
        }
    }
}

// ---------------- fused MFMA attention (softmax over batch axis) ----------------
// P0 = sigmoid((S0-S1)/8); O0 = P0.V0; O1 = colsum(V1) - P0.V1.
// Qb,Kb: [B][S][1024] bf16; VT: [B][H][64][2048] bf16; Cc: [B][S][1024] bf16.
__global__ __launch_bounds__(256) void attn_mfma(
    const u16* __restrict__ Qb, const u16* __restrict__ Kb,
    const u16* __restrict__ VT, u16* __restrict__ Cc)
{
    __shared__ __attribute__((aligned(16))) u16 Qs[2][64][72];
    __shared__ __attribute__((aligned(16))) u16 Ks[2][64][72];
    __shared__ __attribute__((aligned(16))) u16 Vs[2][64][72];
    __shared__ __attribute__((aligned(16))) u16 Ps[64][72];

    const int tid = threadIdx.x;
    const int lane = tid & 63;
    const int wave = tid >> 6;       // 0..3
    const int quad = lane >> 4;
    const int l16 = lane & 15;
    const int s0 = blockIdx.x * 64;
    const int h = blockIdx.y;
    const int sw = wave * 16;        // wave's 16-row s-strip

    const int r_ = tid >> 2;         // 0..63 staging row
    const int cq = (tid & 3) * 16;   // staging col quarter

    // ---- stage Q (both batches), then hoist Q fragments to registers ----
    #pragma unroll
    for (int b = 0; b < 2; ++b) {
        const u16* p = Qb + (size_t)(b * S_ + s0 + r_) * 1024 + h * 64 + cq;
        *(uint4*)&Qs[b][r_][cq]     = *(const uint4*)p;
        *(uint4*)&Qs[b][r_][cq + 8] = *(const uint4*)(p + 8);
    }
    __syncthreads();
    bf16x8 qf[2][2];   // [b][ks]
    #pragma unroll
    for (int b = 0; b < 2; ++b)
        #pragma unroll
        for (int ks = 0; ks < 2; ++ks)
            qf[b][ks] = *(const bf16x8*)&Qs[b][sw + l16][ks * 32 + quad * 8];

    f32x4 O0[4] = {}, T1[4] = {};    // [dk-tile]
    float csum = 0.0f;               // partial colsum of V1 for dk row r_

    for (int t0 = 0; t0 < S_; t0 += 64) {
        __syncthreads();   // prior iter's reads of Ks/Vs complete
        #pragma unroll
        for (int b = 0; b < 2; ++b) {
            const u16* pk = Kb + (size_t)(b * S_ + t0 + r_) * 1024 + h * 64 + cq;
            *(uint4*)&Ks[b][r_][cq]     = *(const uint4*)pk;
            *(uint4*)&Ks[b][r_][cq + 8] = *(const uint4*)(pk + 8);
            const u16* pv = VT + ((size_t)(b * H_ + h) * 64 + r_) * 2048 + t0 + cq;
            uint4 v0 = *(const uint4*)pv;
            uint4 v1 = *(const uint4*)(pv + 8);
            *(uint4*)&Vs[b][r_][cq]     = v0;
            *(uint4*)&Vs[b][r_][cq + 8] = v1;
            if (b == 1) {   // accumulate colsum(V1) for this dk row
                const u32* w = (const u32*)&v0;
                #pragma unroll
                for (int i = 0; i < 4; ++i)
                    csum += bf2f((u16)w[i]) + bf2f((u16)(w[i] >> 16));
                w = (const u32*)&v1;
                #pragma unroll
                for (int i = 0; i < 4; ++i)
                    csum += bf2f((u16)w[i]) + bf2f((u16)(w[i] >> 16));
            }
        }
        __syncthreads();

        // ---- QK^T for both batches: S tiles 16(s) x 64(t) per wave ----
        f32x4 a0[4] = {}, a1[4] = {};
        #pragma unroll
        for (int nt = 0; nt < 4; ++nt) {
            #pragma unroll
            for (int ks = 0; ks < 2; ++ks) {
                bf16x8 k0f = *(const bf16x8*)&Ks[0][nt * 16 + l16][ks * 32 + quad * 8];
                bf16x8 k1f = *(const bf16x8*)&Ks[1][nt * 16 + l16][ks * 32 + quad * 8];
                a0[nt] = __builtin_amdgcn_mfma_f32_16x16x32_bf16(qf[0][ks], k0f, a0[nt], 0, 0, 0);
                a1[nt] = __builtin_amdgcn_mfma_f32_16x16x32_bf16(qf[1][ks], k1f, a1[nt], 0, 0, 0);
            }
        }
        // ---- P = sigmoid((S0-S1)/8) -> LDS (wave-private strip) ----
        #pragma unroll
        for (int nt = 0; nt < 4; ++nt) {
            #pragma unroll
            for (int r = 0; r < 4; ++r) {
                float dlt = (a0[nt][r] - a1[nt][r]) * 0.125f;
                float pv = 1.0f / (1.0f + __expf(-dlt));
                Ps[sw + quad * 4 + r][nt * 16 + l16] = f2bf(pv);
            }
        }
        // ---- PV: O0 += P.V0 ; T1 += P.V1 (wave-private P read-back) ----
        bf16x8 pf[2];
        #pragma unroll
        for (int ks = 0; ks < 2; ++ks)
            pf[ks] = *(const bf16x8*)&Ps[sw + l16][ks * 32 + quad * 8];
        #pragma unroll
        for (int nt = 0; nt < 4; ++nt) {
            #pragma unroll
            for (int ks = 0; ks < 2; ++ks) {
                bf16x8 v0f = *(const bf16x8*)&Vs[0][nt * 16 + l16][ks * 32 + quad * 8];
                bf16x8 v1f = *(const bf16x8*)&Vs[1][nt * 16 + l16][ks * 32 + quad * 8];
                O0[nt] = __builtin_amdgcn_mfma_f32_16x16x32_bf16(pf[ks], v0f, O0[nt], 0, 0, 0);
                T1[nt] = __builtin_amdgcn_mfma_f32_16x16x32_bf16(pf[ks], v1f, T1[nt], 0, 0, 0);
            }
        }
    }

    // ---- colsum(V1) reduce (overlay on Ps) and epilogue ----
    __syncthreads();
    float* cs = (float*)&Ps[0][0];          // [64][4] partials
    cs[r_ * 4 + (tid & 3)] = csum;
    __syncthreads();
    #pragma unroll
    for (int nt = 0; nt < 4; ++nt) {
        const int dk = nt * 16 + l16;
        const float cs1 = cs[dk * 4 + 0] + cs[dk * 4 + 1] + cs[dk * 4 + 2] + cs[dk * 4 + 3];
        #pragma unroll
        for (int r = 0; r < 4; ++r) {
            const int s = s0 + sw + quad * 4 + r;
            Cc[(size_t)(0 * S_ + s) * 1024 + h * 64 + dk] = f2bf(O0[nt][r]);
            Cc[(size_t)(1 * S_ + s) * 1024 + h * 64 + dk] = f2bf(cs1 - T1[nt][r]);
        }
    }
}

extern "C" void kernel_launch(void* const* d_in, const int* in_sizes, int n_in,
                              void* d_out, int out_size, void* d_ws, size_t ws_size,
                              hipStream_t stream) {
    const float* q  = (const float*)d_in[0];
    const float* k  = (const float*)d_in[1];
    const float* v  = (const float*)d_in[2];
    const float* Wq = (const float*)d_in[3];
    const float* bq = (const float*)d_in[4];
    const float* Wk = (const float*)d_in[5];
    const float* bk = (const float*)d_in[6];
    const float* Wv = (const float*)d_in[7];
    const float* bv = (const float*)d_in[8];
    const float* Wo = (const float*)d_in[9];
    const float* bo = (const float*)d_in[10];

    char* ws = (char*)d_ws;
    const size_t MB = 1024 * 1024;
    u16* Xb  = (u16*)(ws);             // 8 MB, reused for q/k/v inputs then Cc
    u16* WqT = (u16*)(ws + 8  * MB);   // 2 MB each
    u16* WkT = (u16*)(ws + 10 * MB);
    u16* WvT = (u16*)(ws + 12 * MB);
    u16* WoT = (u16*)(ws + 14 * MB);
    u16* Qp  = (u16*)(ws + 16 * MB);   // 8 MB
    u16* Kp  = (u16*)(ws + 24 * MB);   // 8 MB
    u16* Vp  = (u16*)(ws + 32 * MB);   // 8 MB
    u16* VTv = (u16*)(ws + 40 * MB);   // 8 MB
    u16* Cc  = Xb;                     // reuse (X dead after V projection)
    float* out = (float*)d_out;

    dim3 blk(256);
    const int NEL = BS_ * D_;          // 4M elements

    // weight transposes (independent of inputs)
    transpose_w<<<dim3(16, 16), blk, 0, stream>>>(Wq, WqT, 1);
    transpose_w<<<dim3(16, 16), blk, 0, stream>>>(Wk, WkT, 1);
    transpose_w<<<dim3(16, 16), blk, 0, stream>>>(Wv, WvT, 1);
    transpose_w<<<dim3(16, 16), blk, 0, stream>>>(Wo, WoT, 0);

    // q projection
    convert_bf16<<<dim3(NEL / (256 * 8)), blk, 0, stream>>>(q, Xb, NEL);
    gemm_bt<<<dim3(32, 8), blk, 0, stream>>>(Xb, WqT, bq, (void*)Qp, 0);
    // k projection
    convert_bf16<<<dim3(NEL / (256 * 8)), blk, 0, stream>>>(k, Xb, NEL);
    gemm_bt<<<dim3(32, 8), blk, 0, stream>>>(Xb, WkT, bk, (void*)Kp, 0);
    // v projection
    convert_bf16<<<dim3(NEL / (256 * 8)), blk, 0, stream>>>(v, Xb, NEL);
    gemm_bt<<<dim3(32, 8), blk, 0, stream>>>(Xb, WvT, bv, (void*)Vp, 0);

    transpose_v<<<dim3(32, 32), blk, 0, stream>>>(Vp, VTv);
    attn_mfma<<<dim3(32, 16), blk, 0, stream>>>(Qp, Kp, VTv, Cc);
    gemm_bt<<<dim3(32, 8), blk, 0, stream>>>(Cc, WoT, bo, d_out, 1);
}